// Round 12
// baseline (117.716 us; speedup 1.0000x reference)
//
#include <hip/hip_runtime.h>
#include <math.h>

// Problem constants
#define NB 128     // batch
#define NR 1152    // routes
#define NC 10      // capsules
#define NBLK 480   // 10 c x 24 rch x 2 bh
#define NPC  48    // blocks per capsule

typedef __attribute__((ext_vector_type(8))) short bf16x8;
typedef __attribute__((ext_vector_type(16))) float f32x16;

__device__ __forceinline__ unsigned pk_bf16(float a, float b) {
    unsigned r;
    asm("v_cvt_pk_bf16_f32 %0, %1, %2" : "=v"(r) : "v"(a), "v"(b));
    return r;
}

union UF { uint4 q; unsigned u[4]; bf16x8 v; };

// ------------------------------------------------------------------
// mainloop: on-the-fly bf16x3 + 32x32x16 MFMA pred + route reduce.
// ONE batch-group (32) per wave. A = W (M=o), B = x (N=b).
// C: col(l&31)=b, row(reg&3)+8*(reg>>2)+4*hi1=o.
// MODE 0: uniform sum (MFMA-chained); x direct; owner lanes write xts
//         bf16 hi/lo planes ((lr0+rr)%10 == c).
// MODE 1: x fragments from xts; d = pred.ov, e = exp(d-20), Z += e,
//         acc += e*pred.
// ------------------------------------------------------------------
template<int MODE>
__device__ __forceinline__ void mainloop(const float* __restrict__ x,
                                         const float* __restrict__ W,
                                         uint4* __restrict__ xt4,
                                         int c, int r0, int bq, int lo5, int hi1,
                                         int lr0,
                                         const float (&ov)[16],
                                         f32x16& acc, float& Z)
{
    f32x16 zz;
#pragma unroll
    for (int j = 0; j < 16; ++j) { acc[j] = 0.f; zz[j] = 0.f; }
    Z = 0.f;
    const float* wb = W + ((size_t)(c * NR + r0) * 16 + hi1 * 8) * 32 + lo5;
    const float* xp = (MODE == 0) ? x + ((size_t)bq * NR + r0) * 16 + hi1 * 8 : nullptr;

#pragma unroll 3
    for (int rr = 0; rr < 12; ++rr) {
        // ---- W fragment: 8 lane-coalesced f32 -> hi/lo bf16 planes ----
        float wv[8];
#pragma unroll
        for (int j = 0; j < 8; ++j) wv[j] = wb[(size_t)rr * 512 + j * 32];
        UF Ah, Al, Xh, Xl;
#pragma unroll
        for (int j = 0; j < 4; ++j) Ah.u[j] = pk_bf16(wv[2*j], wv[2*j+1]);
#pragma unroll
        for (int j = 0; j < 4; ++j) {
            float g0 = __uint_as_float(Ah.u[j] << 16);
            float g1 = __uint_as_float(Ah.u[j] & 0xffff0000u);
            Al.u[j] = pk_bf16(wv[2*j] - g0, wv[2*j+1] - g1);
        }
        const size_t rb4 = ((size_t)((r0 + rr) * 2 + hi1) * 2) * 128;
        if (MODE == 0) {
            float4 u0 = *(const float4*)(xp + rr * 16);
            float4 u1 = *(const float4*)(xp + rr * 16 + 4);
            float xv[8] = {u0.x,u0.y,u0.z,u0.w, u1.x,u1.y,u1.z,u1.w};
#pragma unroll
            for (int j = 0; j < 4; ++j) Xh.u[j] = pk_bf16(xv[2*j], xv[2*j+1]);
#pragma unroll
            for (int j = 0; j < 4; ++j) {
                float g0 = __uint_as_float(Xh.u[j] << 16);
                float g1 = __uint_as_float(Xh.u[j] & 0xffff0000u);
                Xl.u[j] = pk_bf16(xv[2*j] - g0, xv[2*j+1] - g1);
            }
            if (((lr0 + rr) % 10) == c) {
                xt4[rb4 + bq]       = Xh.q;
                xt4[rb4 + 128 + bq] = Xl.q;
            }
            acc = __builtin_amdgcn_mfma_f32_32x32x16_bf16(Ah.v, Xh.v, acc, 0, 0, 0);
            acc = __builtin_amdgcn_mfma_f32_32x32x16_bf16(Al.v, Xh.v, acc, 0, 0, 0);
            acc = __builtin_amdgcn_mfma_f32_32x32x16_bf16(Ah.v, Xl.v, acc, 0, 0, 0);
        } else {
            Xh.q = xt4[rb4 + bq];
            Xl.q = xt4[rb4 + 128 + bq];
            f32x16 q;
            q = __builtin_amdgcn_mfma_f32_32x32x16_bf16(Ah.v, Xh.v, zz, 0, 0, 0);
            q = __builtin_amdgcn_mfma_f32_32x32x16_bf16(Al.v, Xh.v, q, 0, 0, 0);
            q = __builtin_amdgcn_mfma_f32_32x32x16_bf16(Ah.v, Xl.v, q, 0, 0, 0);
            float d0 = 0.f, d1 = 0.f;
#pragma unroll
            for (int j = 0; j < 8; ++j) {
                d0 = fmaf(q[2*j],   ov[2*j],   d0);
                d1 = fmaf(q[2*j+1], ov[2*j+1], d1);
            }
            float d = d0 + d1;
            d += __shfl_xor(d, 32);
            float e = __expf(d - 20.0f);
            Z += e;
#pragma unroll
            for (int j = 0; j < 16; ++j) acc[j] = fmaf(e, q[j], acc[j]);
        }
    }
}

// ------------------------------------------------------------------
// chunk_add: 8-wave XOR-swizzled LDS merge (4 h-slices x [64][32]) of the
// block's chunk, then agent-scope atomicAdd into the per-capsule
// accumulator (sc 16KB full-batch, zc 512B). Proven pattern (r10/r11).
// ------------------------------------------------------------------
template<int WITHZ>
__device__ __forceinline__ void chunk_add(const f32x16& acc, float Z,
    int t, int l, int h, int bp, int bh, int lo5, int hi1,
    float* lds, float* __restrict__ sc, float* __restrict__ zc)
{
    const int bl = bp * 32 + lo5;
    __syncthreads();
#pragma unroll
    for (int j = 0; j < 16; ++j) {
        int orow = (j & 3) + 8 * (j >> 2) + 4 * hi1;
        lds[h * 2048 + bl * 32 + (orow ^ lo5)] = acc[j];
    }
    __syncthreads();
#pragma unroll
    for (int k = 0; k < 4; ++k) {
        int idx = t + 512 * k;
        int b2 = idx >> 5, o = idx & 31;
        float s = 0.f;
#pragma unroll
        for (int hh = 0; hh < 4; ++hh)
            s += lds[hh * 2048 + b2 * 32 + (o ^ (b2 & 31))];
        (void)__hip_atomic_fetch_add(sc + (size_t)(bh * 64 + b2) * 32 + o, s,
                                     __ATOMIC_RELAXED, __HIP_MEMORY_SCOPE_AGENT);
    }
    if (WITHZ) {
        __syncthreads();
        if (l < 32) lds[8192 + h * 64 + bp * 32 + l] = Z;
        __syncthreads();
        if (t < 64) {
            float z = lds[8192 + t] + lds[8256 + t] + lds[8320 + t] + lds[8384 + t];
            (void)__hip_atomic_fetch_add(zc + bh * 64 + t, z,
                                         __ATOMIC_RELAXED, __HIP_MEMORY_SCOPE_AGENT);
        }
    }
}

// ------------------------------------------------------------------
// merge_squash: read the 16KB per-capsule sum (+512B Z) with agent atomic
// loads (coherence point -> never stale), normalize, squash over batch.
// Leaves out staged in lds[b*33+o], factor in lds[5008+o]; sv = this
// thread's pre-factor values.
// ------------------------------------------------------------------
template<int M>
__device__ __forceinline__ void merge_squash(const float* __restrict__ sc,
                                             const float* __restrict__ zc,
                                             int t, float* lds, float (&sv)[8])
{
    if (M >= 1 && t < NB)
        lds[5120 + t] = __hip_atomic_load(zc + t, __ATOMIC_RELAXED,
                                          __HIP_MEMORY_SCOPE_AGENT);
    __syncthreads();
    float pn = 0.f;
#pragma unroll
    for (int k = 0; k < 8; ++k) {
        int idx = t + 512 * k;
        float s = __hip_atomic_load(sc + idx, __ATOMIC_RELAXED,
                                    __HIP_MEMORY_SCOPE_AGENT);
        float v = (M == 0) ? s * (1.0f / 1152.0f) : s / lds[5120 + (idx >> 5)];
        sv[k] = v;
        pn = fmaf(v, v, pn);
        lds[(idx >> 5) * 33 + (idx & 31)] = v;
    }
    lds[4480 + (t >> 5) * 33 + (t & 31)] = pn;
    __syncthreads();
    if (t < 32) {
        float n2 = 0.f;
#pragma unroll
        for (int m = 0; m < 16; ++m) n2 += lds[4480 + m * 33 + t];
        lds[5008 + t] = sqrtf(n2) / (1.0f + n2);   // (n2/(1+n2))/sqrt(n2)
    }
    __syncthreads();
}

// ------------------------------------------------------------------
// routing_k: the WHOLE routing layer in one kernel. 480 blocks x 512 thr
// (8 waves = 4 h-route-quarters x 2 bp-batch-groups; block = (c,rch,bh)).
// __launch_bounds__(512,4): VGPR<=128 -> 2 blocks/CU -> capacity 512 >= 480
// -> all blocks co-resident -> atomic spin barriers cannot deadlock.
// Phase 0 (uniform, writes xts) -> GLOBAL barrier (cnt[0]==480) ->
// redundant 16KB merge -> phase 1 -> per-capsule barrier (48) -> merge ->
// phase 2 -> sign-off; one writer block per capsule merges + writes dout.
// All cross-block data flows through agent-scope atomics (coherence
// point); xts plain stores are same-XCD L2 (swizzle) + vmcnt-drained.
// ------------------------------------------------------------------
__global__ __launch_bounds__(512, 4) void routing_k(const float* __restrict__ x,
                                                    const float* __restrict__ W,
                                                    unsigned* __restrict__ xts,
                                                    float* __restrict__ dout,
                                                    float* __restrict__ sb,
                                                    float* __restrict__ zb,
                                                    int* __restrict__ cnt)
{
    __shared__ float lds[16384];   // 64 KB
    const int pb = blockIdx.x;
    const int lin = (pb & 7) * 60 + (pb >> 3);   // 480 = 8*60, XCD-chunked
    const int c   = lin % 10;
    const int qq  = lin / 10;                    // rch*2 + bh
    const int bh  = qq & 1;
    const int rch = qq >> 1;
    const int t = threadIdx.x;
    const int w = t >> 6, l = t & 63;
    const int h = w >> 1, bp = w & 1;
    const int lo5 = l & 31, hi1 = l >> 5;
    const int r0 = rch * 48 + h * 12;
    const int bq = bh * 64 + bp * 32 + lo5;      // this wave's batch
    uint4* xt4 = (uint4*)xts;

    float ov[16], sv[8];
    f32x16 acc; float Z;
#pragma unroll
    for (int j = 0; j < 16; ++j) ov[j] = 0.f;

    // ---- phase 0: uniform ----
    mainloop<0>(x, W, xt4, c, r0, bq, lo5, hi1, h * 12, ov, acc, Z);
    chunk_add<0>(acc, Z, t, l, h, bp, bh, lo5, hi1, lds,
                 sb + (size_t)c * 4096, nullptr);
    // global barrier: all 480 blocks done with phase 0 (sb0 + xts complete)
    __syncthreads();
    if (t == 0) {
        __hip_atomic_fetch_add(&cnt[0], 1, __ATOMIC_RELAXED, __HIP_MEMORY_SCOPE_AGENT);
        while (__hip_atomic_load(&cnt[0], __ATOMIC_RELAXED,
                                 __HIP_MEMORY_SCOPE_AGENT) < NBLK)
            __builtin_amdgcn_s_sleep(8);
    }
    __syncthreads();
    merge_squash<0>(sb + (size_t)c * 4096, nullptr, t, lds, sv);
#pragma unroll
    for (int j = 0; j < 16; ++j) {
        int orow = (j & 3) + 8 * (j >> 2) + 4 * hi1;
        ov[j] = lds[bq * 33 + orow] * lds[5008 + orow];
    }

    // ---- phase 1: softmax(pred . out0) ----
    float* sc1 = sb + (size_t)(NC + c) * 4096;
    float* zc1 = zb + (size_t)c * 128;
    mainloop<1>(nullptr, W, xt4, c, r0, bq, lo5, hi1, 0, ov, acc, Z);
    chunk_add<1>(acc, Z, t, l, h, bp, bh, lo5, hi1, lds, sc1, zc1);
    __syncthreads();
    if (t == 0) {
        __hip_atomic_fetch_add(&cnt[1 + c], 1, __ATOMIC_RELAXED, __HIP_MEMORY_SCOPE_AGENT);
        while (__hip_atomic_load(&cnt[1 + c], __ATOMIC_RELAXED,
                                 __HIP_MEMORY_SCOPE_AGENT) < NPC)
            __builtin_amdgcn_s_sleep(8);
    }
    __syncthreads();
    merge_squash<1>(sc1, zc1, t, lds, sv);
#pragma unroll
    for (int j = 0; j < 16; ++j) {
        int orow = (j & 3) + 8 * (j >> 2) + 4 * hi1;
        ov[j] += lds[bq * 33 + orow] * lds[5008 + orow];
    }

    // ---- phase 2: softmax(pred . (out0+out1)) ----
    float* sc2 = sb + (size_t)(2 * NC + c) * 4096;
    float* zc2 = zb + (size_t)(NC + c) * 128;
    mainloop<1>(nullptr, W, xt4, c, r0, bq, lo5, hi1, 0, ov, acc, Z);
    chunk_add<1>(acc, Z, t, l, h, bp, bh, lo5, hi1, lds, sc2, zc2);
    __syncthreads();
    if (t == 0)
        __hip_atomic_fetch_add(&cnt[11 + c], 1, __ATOMIC_RELAXED,
                               __HIP_MEMORY_SCOPE_AGENT);
    if (rch != 0 || bh != 0) return;   // non-writers retire
    if (t == 0) {
        while (__hip_atomic_load(&cnt[11 + c], __ATOMIC_RELAXED,
                                 __HIP_MEMORY_SCOPE_AGENT) < NPC)
            __builtin_amdgcn_s_sleep(8);
    }
    __syncthreads();
    merge_squash<2>(sc2, zc2, t, lds, sv);
    const float ff = lds[5008 + (t & 31)];
#pragma unroll
    for (int k = 0; k < 8; ++k)
        dout[(size_t)c * 4096 + t + 512 * k] = sv[k] * ff;
}

// ------------------------------------------------------------------
extern "C" void kernel_launch(void* const* d_in, const int* in_sizes, int n_in,
                              void* d_out, int out_size, void* d_ws, size_t ws_size,
                              hipStream_t stream)
{
    (void)in_sizes; (void)n_in; (void)out_size; (void)ws_size;
    const float* x = (const float*)d_in[0];
    const float* W = (const float*)d_in[1];
    float* wsf  = (float*)d_ws;
    float* outf = (float*)d_out;

    // ws layout (32-bit units):
    // xts 2,359,296 | sb 3x40,960 | zb 2x1,280 | cnt 64   (~9.9 MB)
    unsigned* xts = (unsigned*)d_ws;
    float* sb  = wsf + 2359296;
    float* zb  = sb + 3 * NC * 4096;
    int*   cnt = (int*)(zb + 2 * NC * 128);

    // zero accumulators + counters (ws is poisoned to 0xAA once)
    hipMemsetAsync(sb, 0, (size_t)(3 * NC * 4096 + 2 * NC * 128 + 64) * 4, stream);

    // whole routing layer in one dispatch
    routing_k<<<NBLK, 512, 0, stream>>>(x, W, xts, outf, sb, zb, cnt);
}

// Round 13
// 85.928 us; speedup vs baseline: 1.3699x; 1.3699x over previous
//
#include <hip/hip_runtime.h>
#include <math.h>

// Problem constants
#define NB 128     // batch
#define NR 1152    // routes
#define NC 10      // capsules
#define NBLK 240   // 10 c x 4 bh x 6 rs

typedef __attribute__((ext_vector_type(8))) short bf16x8;
typedef __attribute__((ext_vector_type(16))) float f32x16;

__device__ __forceinline__ unsigned pk_bf16(float a, float b) {
    unsigned r;
    asm("v_cvt_pk_bf16_f32 %0, %1, %2" : "=v"(r) : "v"(a), "v"(b));
    return r;
}

union UF { uint4 q; unsigned u[4]; bf16x8 v; };

#define MFMA(A, B, C) __builtin_amdgcn_mfma_f32_32x32x16_bf16((A).v, (B).v, (C), 0, 0, 0)

// ------------------------------------------------------------------
// mainloop24: on-the-fly bf16x3 + 32x32x16 MFMA pred + route reduce.
// One 32-batch group per wave, 24 routes per wave.
// A = W (M=o), B = x (N=b). C: col(l&31)=b, row(reg&3)+8*(reg>>2)+4*hi1=o.
// MODE 0: uniform sum (MFMA-chained); x read direct (scattered); owner
//         lanes ((r%10)==c) write xts bf16 hi/lo planes via per-dword
//         agent atomic stores (write-through -> mapping-independent vis).
// MODE 1: x fragments from xts (plain loads; lines never stale: written
//         at coherence point, first touched after the global barrier);
//         d = pred.ov, e = exp(d-20), Z += e, acc += e*pred.
// ------------------------------------------------------------------
template<int MODE>
__device__ __forceinline__ void mainloop24(const float* __restrict__ x,
                                           const float* __restrict__ W,
                                           unsigned* __restrict__ xts,
                                           int c, int r0, int bq, int lo5, int hi1,
                                           const float (&ov)[16],
                                           f32x16& acc, float& Z)
{
    f32x16 zz;
#pragma unroll
    for (int j = 0; j < 16; ++j) { acc[j] = 0.f; zz[j] = 0.f; }
    Z = 0.f;
    const float* wb = W + ((size_t)(c * NR + r0) * 16 + hi1 * 8) * 32 + lo5;
    const float* xp = (MODE == 0) ? x + ((size_t)bq * NR + r0) * 16 + hi1 * 8 : nullptr;
    const uint4* xt4 = (const uint4*)xts;

#pragma unroll 3
    for (int rr = 0; rr < 24; ++rr) {
        // ---- W fragment: 8 lane-coalesced f32 -> hi/lo bf16 planes ----
        float wv[8];
#pragma unroll
        for (int j = 0; j < 8; ++j) wv[j] = wb[(size_t)rr * 512 + j * 32];
        UF Ah, Al, Xh, Xl;
#pragma unroll
        for (int j = 0; j < 4; ++j) Ah.u[j] = pk_bf16(wv[2*j], wv[2*j+1]);
#pragma unroll
        for (int j = 0; j < 4; ++j) {
            float g0 = __uint_as_float(Ah.u[j] << 16);
            float g1 = __uint_as_float(Ah.u[j] & 0xffff0000u);
            Al.u[j] = pk_bf16(wv[2*j] - g0, wv[2*j+1] - g1);
        }
        const size_t rb4 = ((size_t)((r0 + rr) * 2 + hi1) * 2) * 128;
        if (MODE == 0) {
            float4 u0 = *(const float4*)(xp + rr * 16);
            float4 u1 = *(const float4*)(xp + rr * 16 + 4);
            float xv[8] = {u0.x,u0.y,u0.z,u0.w, u1.x,u1.y,u1.z,u1.w};
#pragma unroll
            for (int j = 0; j < 4; ++j) Xh.u[j] = pk_bf16(xv[2*j], xv[2*j+1]);
#pragma unroll
            for (int j = 0; j < 4; ++j) {
                float g0 = __uint_as_float(Xh.u[j] << 16);
                float g1 = __uint_as_float(Xh.u[j] & 0xffff0000u);
                Xl.u[j] = pk_bf16(xv[2*j] - g0, xv[2*j+1] - g1);
            }
            if (((r0 + rr) % 10) == c) {
                unsigned* xw = xts + (rb4 + bq) * 4;
                unsigned* xw2 = xts + (rb4 + 128 + bq) * 4;
#pragma unroll
                for (int j = 0; j < 4; ++j) {
                    __hip_atomic_store(xw + j, Xh.u[j], __ATOMIC_RELAXED,
                                       __HIP_MEMORY_SCOPE_AGENT);
                    __hip_atomic_store(xw2 + j, Xl.u[j], __ATOMIC_RELAXED,
                                       __HIP_MEMORY_SCOPE_AGENT);
                }
            }
            acc = MFMA(Ah, Xh, acc);
            acc = MFMA(Al, Xh, acc);
            acc = MFMA(Ah, Xl, acc);
        } else {
            Xh.q = xt4[rb4 + bq];
            Xl.q = xt4[rb4 + 128 + bq];
            f32x16 q;
            q = MFMA(Ah, Xh, zz);
            q = MFMA(Al, Xh, q);
            q = MFMA(Ah, Xl, q);
            float d0 = 0.f, d1 = 0.f;
#pragma unroll
            for (int j = 0; j < 8; ++j) {
                d0 = fmaf(q[2*j],   ov[2*j],   d0);
                d1 = fmaf(q[2*j+1], ov[2*j+1], d1);
            }
            float d = d0 + d1;
            d += __shfl_xor(d, 32);      // combine k-halves (same batch)
            float e = __expf(d - 20.0f);
            Z += e;
#pragma unroll
            for (int j = 0; j < 16; ++j) acc[j] = fmaf(e, q[j], acc[j]);
        }
    }
}

// ------------------------------------------------------------------
// block_reduce_add: 8-wave XOR-swizzled LDS reduce of the block's
// [32b][32o] tile, then agent atomicAdd into the (c,bh) group accumulator
// (nbg 4KB, zbg 128B). 6-way contention only.
// ------------------------------------------------------------------
template<int WITHZ>
__device__ __forceinline__ void block_reduce_add(const f32x16& acc, float Z,
    int t, int l, int h, int lo5, int hi1, float* lds,
    float* __restrict__ nbg, float* __restrict__ zbg)
{
    __syncthreads();
#pragma unroll
    for (int j = 0; j < 16; ++j) {
        int orow = (j & 3) + 8 * (j >> 2) + 4 * hi1;
        lds[h * 1024 + lo5 * 32 + (orow ^ lo5)] = acc[j];
    }
    if (WITHZ && l < 32) lds[8192 + h * 32 + lo5] = Z;
    __syncthreads();
#pragma unroll
    for (int k = 0; k < 2; ++k) {
        int idx = t + 512 * k;
        int b = idx >> 5, o = idx & 31;
        float s = 0.f;
#pragma unroll
        for (int hh = 0; hh < 8; ++hh)
            s += lds[hh * 1024 + b * 32 + (o ^ b)];
        (void)__hip_atomic_fetch_add(nbg + idx, s, __ATOMIC_RELAXED,
                                     __HIP_MEMORY_SCOPE_AGENT);
    }
    if (WITHZ && t < 32) {
        float z = 0.f;
#pragma unroll
        for (int hh = 0; hh < 8; ++hh) z += lds[8192 + hh * 32 + t];
        (void)__hip_atomic_fetch_add(zbg + t, z, __ATOMIC_RELAXED,
                                     __HIP_MEMORY_SCOPE_AGENT);
    }
}

// ------------------------------------------------------------------
// squash_exchange: read back the 4KB group numerator (+Z), normalize ->
// s staged in lds[b*33+o]; capsule n2 via 32-float atomicAdd from rs==0
// blocks + 4-target spin; factor f in lds[1088+o].
// Caller must have passed the group barrier (nbg/zbg complete).
// ------------------------------------------------------------------
template<int P>
__device__ __forceinline__ void squash_exchange(
    const float* __restrict__ nbg, const float* __restrict__ zbg,
    float* __restrict__ n2c, int* __restrict__ cntn,
    int t, int rs, float* lds)
{
    if (P >= 1 && t < 32)
        lds[1056 + t] = __hip_atomic_load(zbg + t, __ATOMIC_RELAXED,
                                          __HIP_MEMORY_SCOPE_AGENT);
    __syncthreads();
#pragma unroll
    for (int k = 0; k < 2; ++k) {
        int idx = t + 512 * k;
        float s = __hip_atomic_load(nbg + idx, __ATOMIC_RELAXED,
                                    __HIP_MEMORY_SCOPE_AGENT);
        float v = (P == 0) ? s * (1.0f / 1152.0f) : s / lds[1056 + (idx >> 5)];
        lds[(idx >> 5) * 33 + (idx & 31)] = v;
    }
    __syncthreads();
    if (t < 32 && rs == 0) {
        float n2 = 0.f;
#pragma unroll
        for (int b = 0; b < 32; ++b) {
            float v = lds[b * 33 + t];
            n2 = fmaf(v, v, n2);
        }
        (void)__hip_atomic_fetch_add(n2c + t, n2, __ATOMIC_RELAXED,
                                     __HIP_MEMORY_SCOPE_AGENT);
    }
    __syncthreads();   // drain wave-0 adds before sign-off
    if (t == 0) {
        if (rs == 0)
            __hip_atomic_fetch_add(cntn, 1, __ATOMIC_RELAXED,
                                   __HIP_MEMORY_SCOPE_AGENT);
        while (__hip_atomic_load(cntn, __ATOMIC_RELAXED,
                                 __HIP_MEMORY_SCOPE_AGENT) < 4)
            __builtin_amdgcn_s_sleep(2);
    }
    __syncthreads();
    if (t < 32) {
        float n2t = __hip_atomic_load(n2c + t, __ATOMIC_RELAXED,
                                      __HIP_MEMORY_SCOPE_AGENT);
        lds[1088 + t] = sqrtf(n2t) / (1.0f + n2t);   // (n2/(1+n2))/sqrt(n2)
    }
    __syncthreads();
}

// ------------------------------------------------------------------
// routing2_k: whole routing layer, one dispatch. 240 blocks x 512 thr.
// Block = (c, bh batch-quarter, rs route-sixth); 8 waves = 8 route-slices
// of 24 routes, all on the SAME 32-batch group -> out is block-local
// across phases (registers), no out broadcast. Cross-block exchange per
// phase: 4KB numerator (6-block group), 32-float Z, 32-float n2 (capsule).
// Phase 0 ends with ONE global spin barrier (orders xts + nb0 for all);
// phases 1-2 use 6-target group spins + 4-target n2 spins.
// 240 blocks <= 256 CUs at worst-case 1 block/CU -> co-resident, no
// deadlock. launch_bounds(512,2): VGPR budget 256 (round-11-proven ~92,
// no spill; round 12's (512,4)->64 VGPR spill was the regression).
// ------------------------------------------------------------------
__global__ __launch_bounds__(512, 2) void routing2_k(const float* __restrict__ x,
                                                     const float* __restrict__ W,
                                                     unsigned* __restrict__ xts,
                                                     float* __restrict__ dout,
                                                     float* __restrict__ nb,
                                                     float* __restrict__ zb,
                                                     float* __restrict__ n2g,
                                                     int* __restrict__ cnt)
{
    __shared__ float lds[8448];   // 33 KB
    const int pb = blockIdx.x;
    const int lin = (pb & 7) * 30 + (pb >> 3);   // XCD-chunked (240 = 8*30)
    const int c   = lin % 10;
    const int g4  = lin / 10;                    // 0..23
    const int bh  = g4 & 3;
    const int rs  = g4 >> 2;
    const int grp = c * 4 + bh;                  // numerator group id
    const int t = threadIdx.x;
    const int h = t >> 6, l = t & 63;
    const int lo5 = l & 31, hi1 = l >> 5;
    const int r0 = rs * 192 + h * 24;
    const int bq = bh * 32 + lo5;                // this lane's batch

    float ov[16];
#pragma unroll
    for (int j = 0; j < 16; ++j) ov[j] = 0.f;
    f32x16 acc; float Z;

    // ================= phase 0: uniform =================
    mainloop24<0>(x, W, xts, c, r0, bq, lo5, hi1, ov, acc, Z);
    block_reduce_add<0>(acc, Z, t, l, h, lo5, hi1, lds,
                        nb + (size_t)grp * 1024, nullptr);
    // global barrier: nb0 + xts complete everywhere
    __syncthreads();
    if (t == 0) {
        __hip_atomic_fetch_add(&cnt[0], 1, __ATOMIC_RELAXED, __HIP_MEMORY_SCOPE_AGENT);
        while (__hip_atomic_load(&cnt[0], __ATOMIC_RELAXED,
                                 __HIP_MEMORY_SCOPE_AGENT) < NBLK)
            __builtin_amdgcn_s_sleep(8);
    }
    __syncthreads();
    squash_exchange<0>(nb + (size_t)grp * 1024, nullptr,
                       n2g + (size_t)c * 32, cnt + 81 + c, t, rs, lds);
#pragma unroll
    for (int j = 0; j < 16; ++j) {
        int orow = (j & 3) + 8 * (j >> 2) + 4 * hi1;
        ov[j] = lds[lo5 * 33 + orow] * lds[1088 + orow];
    }

    // ================= phase 1: softmax(pred . out0) =================
    mainloop24<1>(nullptr, W, xts, c, r0, bq, lo5, hi1, ov, acc, Z);
    {
        float* nbg = nb + (size_t)(40 + grp) * 1024;
        float* zbg = zb + (size_t)grp * 32;
        block_reduce_add<1>(acc, Z, t, l, h, lo5, hi1, lds, nbg, zbg);
        __syncthreads();
        if (t == 0) {
            __hip_atomic_fetch_add(&cnt[1 + grp], 1, __ATOMIC_RELAXED,
                                   __HIP_MEMORY_SCOPE_AGENT);
            while (__hip_atomic_load(&cnt[1 + grp], __ATOMIC_RELAXED,
                                     __HIP_MEMORY_SCOPE_AGENT) < 6)
                __builtin_amdgcn_s_sleep(2);
        }
        __syncthreads();
        squash_exchange<1>(nbg, zbg, n2g + (size_t)(10 + c) * 32,
                           cnt + 91 + c, t, rs, lds);
#pragma unroll
        for (int j = 0; j < 16; ++j) {
            int orow = (j & 3) + 8 * (j >> 2) + 4 * hi1;
            ov[j] += lds[lo5 * 33 + orow] * lds[1088 + orow];
        }
    }

    // ================= phase 2: softmax(pred . (out0+out1)) =================
    mainloop24<1>(nullptr, W, xts, c, r0, bq, lo5, hi1, ov, acc, Z);
    {
        float* nbg = nb + (size_t)(80 + grp) * 1024;
        float* zbg = zb + (size_t)(40 + grp) * 32;
        block_reduce_add<1>(acc, Z, t, l, h, lo5, hi1, lds, nbg, zbg);
        __syncthreads();
        if (t == 0)
            __hip_atomic_fetch_add(&cnt[41 + grp], 1, __ATOMIC_RELAXED,
                                   __HIP_MEMORY_SCOPE_AGENT);
        if (rs != 0) return;       // non-writers retire (adds already visible)
        if (t == 0) {
            while (__hip_atomic_load(&cnt[41 + grp], __ATOMIC_RELAXED,
                                     __HIP_MEMORY_SCOPE_AGENT) < 6)
                __builtin_amdgcn_s_sleep(2);
        }
        __syncthreads();
        squash_exchange<2>(nbg, zbg, n2g + (size_t)(20 + c) * 32,
                           cnt + 101 + c, t, 0, lds);
        // write dout: this block owns (c, batch bh*32..bh*32+32)
#pragma unroll
        for (int k = 0; k < 2; ++k) {
            int idx = t + 512 * k;
            float v = lds[(idx >> 5) * 33 + (idx & 31)] * lds[1088 + (idx & 31)];
            dout[(size_t)c * 4096 + (size_t)(bh * 32 + (idx >> 5)) * 32 + (idx & 31)] = v;
        }
    }
}

// ------------------------------------------------------------------
extern "C" void kernel_launch(void* const* d_in, const int* in_sizes, int n_in,
                              void* d_out, int out_size, void* d_ws, size_t ws_size,
                              hipStream_t stream)
{
    (void)in_sizes; (void)n_in; (void)out_size; (void)ws_size;
    const float* x = (const float*)d_in[0];
    const float* W = (const float*)d_in[1];
    float* wsf  = (float*)d_ws;
    float* outf = (float*)d_out;

    // ws layout (32-bit units):
    // xts 2,359,296 | nb 3x40x1024 | zb 2x40x32 | n2g 3x10x32 | cnt 128
    unsigned* xts = (unsigned*)d_ws;
    float* nb  = wsf + 2359296;
    float* zb  = nb + 3 * 40 * 1024;
    float* n2g = zb + 2 * 40 * 32;
    int*   cnt = (int*)(n2g + 3 * 10 * 32);

    // zero accumulators + counters (ws is poisoned to 0xAA once)
    hipMemsetAsync(nb, 0, (size_t)(3 * 40 * 1024 + 2 * 40 * 32 + 3 * 10 * 32 + 128) * 4,
                   stream);

    // whole routing layer in one dispatch
    routing2_k<<<NBLK, 512, 0, stream>>>(x, W, xts, outf, nb, zb, n2g, cnt);
}

// Round 15
// 66.490 us; speedup vs baseline: 1.7704x; 1.2923x over previous
//
#include <hip/hip_runtime.h>
#include <math.h>

// Problem constants
#define NB 128     // batch
#define NR 1152    // routes
#define NC 10      // capsules
#define NCHK 24    // chunks per capsule (route-chunks of 48)

typedef __attribute__((ext_vector_type(8))) short bf16x8;
typedef __attribute__((ext_vector_type(16))) float f32x16;

__device__ __forceinline__ unsigned pk_bf16(float a, float b) {
    unsigned r;
    asm("v_cvt_pk_bf16_f32 %0, %1, %2" : "=v"(r) : "v"(a), "v"(b));
    return r;
}

union UF { uint4 q; unsigned u[4]; bf16x8 v; };

// ------------------------------------------------------------------
// pass_z (round-10 proven structure + wts precompute + unroll 4):
// fused bf16x3 + 32x32x16 MFMA pred + route reduction + folded
// merge/squash epilogue via per-capsule atomic handshake.
// Grid 240 = (10 c x 24 rch of 48 routes), XCD-chunked. 512 thr = 8 waves:
// wave = (h = route-quarter of 12, bp = batch-half of 64).
// A = W (M=o), B = x (N=b). C: col(l&31)=b, row(reg&3)+8*(reg>>2)+4*hi1=o.
// MODE 0: uniform sum; x read direct; owner lanes write xts bf16 planes
//         (plain stores; visible to later DISPATCHES); bp==0 waves also
//         store the W bf16 hi/lo fragments to wts (2 uint4/lane/route).
// MODE 1/2: W fragment = 2 coalesced uint4 loads from wts (replaces 8
//         strided dword loads + ~25 convert VALU); x fragments from xts;
//         d = pred.ov, e = exp(d-20), Z += e, acc += e*pred.
// Epilogue: LDS 4-slice merge -> agent atomicAdd into per-capsule 16KB
// accumulator; __syncthreads (vmcnt drain); fetch_add handshake; last
// block (old==23) reads 16KB sums (agent atomic loads), squashes, writes
// oacc (M0) / oacc+= (M1) / dout (M2).  [proven r10]
// ------------------------------------------------------------------
template<int MODE>
__global__ __launch_bounds__(512, 2) void pass_z(const float* __restrict__ x,
                                                 const float* __restrict__ W,
                                                 unsigned* __restrict__ xts,
                                                 unsigned* __restrict__ wts,
                                                 float* __restrict__ oacc,
                                                 float* __restrict__ dout,
                                                 float* __restrict__ sbuf,
                                                 float* __restrict__ zbuf,
                                                 int* __restrict__ cnt)
{
    __shared__ float lds[16384];   // 64 KB
    __shared__ int lastFlag;
    const int pb = blockIdx.x;
    const int lin = (pb & 7) * 30 + (pb >> 3);   // chunked XCD swizzle (240 = 8*30)
    const int rch = lin / 10;
    const int c   = lin - rch * 10;
    const int t = threadIdx.x;
    const int w = t >> 6, l = t & 63;
    const int h = w >> 1, bp = w & 1;
    const int lo5 = l & 31, hi1 = l >> 5;
    const int r0 = rch * 48 + h * 12;

    if (MODE >= 1) {
        for (int idx = t; idx < 4096; idx += 512)
            lds[(idx >> 5) * 33 + (idx & 31)] = oacc[(size_t)c * 4096 + idx];
    }
    __syncthreads();

    float ov0[16], ov1[16];
    if (MODE >= 1) {
#pragma unroll
        for (int j = 0; j < 16; ++j) {
            int orow = (j & 3) + 8 * (j >> 2) + 4 * hi1;
            ov0[j] = lds[(bp * 64 + lo5) * 33 + orow];
            ov1[j] = lds[(bp * 64 + 32 + lo5) * 33 + orow];
        }
    }

    f32x16 acc0, acc1, zz;
#pragma unroll
    for (int j = 0; j < 16; ++j) { acc0[j] = 0.f; acc1[j] = 0.f; zz[j] = 0.f; }
    float Z0 = 0.f, Z1 = 0.f;

    // W element (r, i=hi1*8+j, o=lo5)
    const float* wb  = W + ((size_t)(c * NR + r0) * 16 + hi1 * 8) * 32 + lo5;
    // direct-x pointers (MODE 0)
    const float* xp0 = x + ((size_t)(bp * 64 + lo5) * NR + r0) * 16 + hi1 * 8;
    const float* xp1 = x + ((size_t)(bp * 64 + 32 + lo5) * NR + r0) * 16 + hi1 * 8;
    // xts uint4-unit addressing: ((r*2+hi1)*2 + plane)*128 + b
    uint4* xt4 = (uint4*)xts;
    // wts uint4-unit addressing: ((c*NR+r)*2 + plane)*64 + l
    uint4* wt4 = (uint4*)wts;
    const int bq0 = bp * 64 + lo5, bq1 = bq0 + 32;

#pragma unroll 4
    for (int rr = 0; rr < 12; ++rr) {
        UF Ah, Al, Xh0, Xl0, Xh1, Xl1;
        const size_t wrow = (size_t)(c * NR + r0 + rr) * 2;
        if (MODE == 0) {
            // ---- W fragment: 8 lane-coalesced f32 -> hi/lo bf16 planes ----
            float wv[8];
#pragma unroll
            for (int j = 0; j < 8; ++j) wv[j] = wb[(size_t)rr * 512 + j * 32];
#pragma unroll
            for (int j = 0; j < 4; ++j) Ah.u[j] = pk_bf16(wv[2*j], wv[2*j+1]);
#pragma unroll
            for (int j = 0; j < 4; ++j) {
                float g0 = __uint_as_float(Ah.u[j] << 16);
                float g1 = __uint_as_float(Ah.u[j] & 0xffff0000u);
                Al.u[j] = pk_bf16(wv[2*j] - g0, wv[2*j+1] - g1);
            }
            // store MFMA-ready W planes (once per (c,r): bp==0 waves only)
            if (bp == 0) {
                wt4[wrow * 64 + l]       = Ah.q;
                wt4[(wrow + 1) * 64 + l] = Al.q;
            }
        } else {
            // ---- W fragment: 2 coalesced uint4 loads (1KB/wave each) ----
            Ah.q = wt4[wrow * 64 + l];
            Al.q = wt4[(wrow + 1) * 64 + l];
        }
        // ---- x fragments ----
        const size_t rb4 = ((size_t)((r0 + rr) * 2 + hi1) * 2) * 128;
        if (MODE == 0) {
            float4 u0 = *(const float4*)(xp0 + rr * 16);
            float4 u1 = *(const float4*)(xp0 + rr * 16 + 4);
            float4 v0 = *(const float4*)(xp1 + rr * 16);
            float4 v1 = *(const float4*)(xp1 + rr * 16 + 4);
            float xv0[8] = {u0.x,u0.y,u0.z,u0.w, u1.x,u1.y,u1.z,u1.w};
            float xv1[8] = {v0.x,v0.y,v0.z,v0.w, v1.x,v1.y,v1.z,v1.w};
#pragma unroll
            for (int j = 0; j < 4; ++j) Xh0.u[j] = pk_bf16(xv0[2*j], xv0[2*j+1]);
#pragma unroll
            for (int j = 0; j < 4; ++j) {
                float g0 = __uint_as_float(Xh0.u[j] << 16);
                float g1 = __uint_as_float(Xh0.u[j] & 0xffff0000u);
                Xl0.u[j] = pk_bf16(xv0[2*j] - g0, xv0[2*j+1] - g1);
            }
#pragma unroll
            for (int j = 0; j < 4; ++j) Xh1.u[j] = pk_bf16(xv1[2*j], xv1[2*j+1]);
#pragma unroll
            for (int j = 0; j < 4; ++j) {
                float g0 = __uint_as_float(Xh1.u[j] << 16);
                float g1 = __uint_as_float(Xh1.u[j] & 0xffff0000u);
                Xl1.u[j] = pk_bf16(xv1[2*j] - g0, xv1[2*j+1] - g1);
            }
            // distributed xts write: this block owns routes (h*12+rr)%10 == c
            if (((h * 12 + rr) % 10) == c) {
                xt4[rb4 + bq0]       = Xh0.q;
                xt4[rb4 + 128 + bq0] = Xl0.q;
                xt4[rb4 + bq1]       = Xh1.q;
                xt4[rb4 + 128 + bq1] = Xl1.q;
            }
        } else {
            Xh0.q = xt4[rb4 + bq0];
            Xl0.q = xt4[rb4 + 128 + bq0];
            Xh1.q = xt4[rb4 + bq1];
            Xl1.q = xt4[rb4 + 128 + bq1];
        }

        if (MODE == 0) {
            acc0 = __builtin_amdgcn_mfma_f32_32x32x16_bf16(Ah.v, Xh0.v, acc0, 0, 0, 0);
            acc0 = __builtin_amdgcn_mfma_f32_32x32x16_bf16(Al.v, Xh0.v, acc0, 0, 0, 0);
            acc0 = __builtin_amdgcn_mfma_f32_32x32x16_bf16(Ah.v, Xl0.v, acc0, 0, 0, 0);
            acc1 = __builtin_amdgcn_mfma_f32_32x32x16_bf16(Ah.v, Xh1.v, acc1, 0, 0, 0);
            acc1 = __builtin_amdgcn_mfma_f32_32x32x16_bf16(Al.v, Xh1.v, acc1, 0, 0, 0);
            acc1 = __builtin_amdgcn_mfma_f32_32x32x16_bf16(Ah.v, Xl1.v, acc1, 0, 0, 0);
        } else {
            f32x16 q0, q1;
            q0 = __builtin_amdgcn_mfma_f32_32x32x16_bf16(Ah.v, Xh0.v, zz, 0, 0, 0);
            q1 = __builtin_amdgcn_mfma_f32_32x32x16_bf16(Ah.v, Xh1.v, zz, 0, 0, 0);
            q0 = __builtin_amdgcn_mfma_f32_32x32x16_bf16(Al.v, Xh0.v, q0, 0, 0, 0);
            q1 = __builtin_amdgcn_mfma_f32_32x32x16_bf16(Al.v, Xh1.v, q1, 0, 0, 0);
            q0 = __builtin_amdgcn_mfma_f32_32x32x16_bf16(Ah.v, Xl0.v, q0, 0, 0, 0);
            q1 = __builtin_amdgcn_mfma_f32_32x32x16_bf16(Ah.v, Xl1.v, q1, 0, 0, 0);
            float d0 = 0.f, d1 = 0.f;
#pragma unroll
            for (int j = 0; j < 16; ++j) {
                d0 = fmaf(q0[j], ov0[j], d0);
                d1 = fmaf(q1[j], ov1[j], d1);
            }
            d0 += __shfl_xor(d0, 32);
            d1 += __shfl_xor(d1, 32);
            float e0 = __expf(d0 - 20.0f);
            float e1 = __expf(d1 - 20.0f);
            Z0 += e0; Z1 += e1;
#pragma unroll
            for (int j = 0; j < 16; ++j) {
                acc0[j] = fmaf(e0, q0[j], acc0[j]);
                acc1[j] = fmaf(e1, q1[j], acc1[j]);
            }
        }
    }

    // ---- 8-wave LDS merge (4 h-slices; b-halves disjoint) ----
    const int b0 = bp * 64 + lo5, b1 = b0 + 32;
    __syncthreads();
#pragma unroll
    for (int j = 0; j < 16; ++j) {
        int orow = (j & 3) + 8 * (j >> 2) + 4 * hi1;
        lds[h * 4096 + b0 * 32 + (orow ^ lo5)] = acc0[j];
        lds[h * 4096 + b1 * 32 + (orow ^ lo5)] = acc1[j];
    }
    __syncthreads();
    // chunk partial -> per-capsule accumulator via agent-scope atomicAdd
    float* sc = sbuf + (size_t)c * 4096;
    for (int idx = t; idx < 4096; idx += 512) {
        int b = idx >> 5, o = idx & 31;
        float s = 0.f;
#pragma unroll
        for (int hh = 0; hh < 4; ++hh)
            s += lds[hh * 4096 + b * 32 + (o ^ (b & 31))];
        (void)__hip_atomic_fetch_add(sc + idx, s, __ATOMIC_RELAXED,
                                     __HIP_MEMORY_SCOPE_AGENT);
    }
    if (MODE >= 1) {
        __syncthreads();
        if (l < 32) {
            lds[h * 128 + bp * 64 + lo5] = Z0;
            lds[h * 128 + bp * 64 + 32 + lo5] = Z1;
        }
        __syncthreads();
        if (t < 128) {
            float z = lds[t] + lds[128 + t] + lds[256 + t] + lds[384 + t];
            (void)__hip_atomic_fetch_add(zbuf + (size_t)c * 128 + t, z,
                                         __ATOMIC_RELAXED, __HIP_MEMORY_SCOPE_AGENT);
        }
    }

    // ---- completion handshake ----
    __syncthreads();   // per-wave vmcnt(0) drain -> all adds at coherence point
    if (t == 0) {
        int old = __hip_atomic_fetch_add(&cnt[c], 1,
                                         __ATOMIC_RELAXED, __HIP_MEMORY_SCOPE_AGENT);
        lastFlag = (old == NCHK - 1) ? 1 : 0;
    }
    __syncthreads();
    if (!lastFlag) return;

    // ===== merger block: read 16KB summed s (+512B z), squash, write =====
    if (MODE >= 1) {
        if (t < NB) {
            lds[8192 + t] = __hip_atomic_load(zbuf + (size_t)c * 128 + t,
                                              __ATOMIC_RELAXED, __HIP_MEMORY_SCOPE_AGENT);
        }
        __syncthreads();
    }
    float sv[8];
    float pn = 0.f;
#pragma unroll
    for (int k = 0; k < 8; ++k) {
        int idx = t + 512 * k;          // o = t&31, b-groups
        float s = __hip_atomic_load(sc + idx, __ATOMIC_RELAXED,
                                    __HIP_MEMORY_SCOPE_AGENT);
        float v = (MODE == 0) ? s * (1.0f / 1152.0f) : s / lds[8192 + (idx >> 5)];
        sv[k] = v;
        pn = fmaf(v, v, pn);
    }
    lds[(t >> 5) * 33 + (t & 31)] = pn;   // 16 groups x 32 o
    __syncthreads();
    if (t < 32) {
        float n2 = 0.f;
#pragma unroll
        for (int m = 0; m < 16; ++m) n2 += lds[m * 33 + t];
        lds[1024 + t] = sqrtf(n2) / (1.0f + n2);   // (n2/(1+n2))/sqrt(n2)
    }
    __syncthreads();
    const float ff = lds[1024 + (t & 31)];
#pragma unroll
    for (int k = 0; k < 8; ++k) {
        int idx = t + 512 * k;
        float v = sv[k] * ff;
        if (MODE == 0)      oacc[(size_t)c * 4096 + idx] = v;
        else if (MODE == 1) oacc[(size_t)c * 4096 + idx] += v;
        else                dout[(size_t)c * 4096 + idx] = v;
    }
}

// ------------------------------------------------------------------
extern "C" void kernel_launch(void* const* d_in, const int* in_sizes, int n_in,
                              void* d_out, int out_size, void* d_ws, size_t ws_size,
                              hipStream_t stream)
{
    (void)in_sizes; (void)n_in; (void)out_size; (void)ws_size;
    const float* x = (const float*)d_in[0];
    const float* W = (const float*)d_in[1];
    float* wsf  = (float*)d_ws;
    float* outf = (float*)d_out;

    // ws layout (32-bit units):
    // xts 2,359,296 | wts 5,898,240 | sbuf 3x40,960 | zbuf 3x1,280 | cnt 32 | oacc
    unsigned* xts = (unsigned*)d_ws;
    unsigned* wts = (unsigned*)d_ws + 2359296;
    float* sb   = wsf + 2359296 + 5898240;
    float* zb   = sb + 3 * 40960;
    int*   cnt  = (int*)(zb + 3 * 1280);
    float* oacc = (float*)(cnt + 32);

    // zero accumulators + counters (ws is poisoned to 0xAA once)
    hipMemsetAsync(sb, 0, (size_t)(3 * 40960 + 3 * 1280 + 32) * 4, stream);

    // iter 0: uniform; owner lanes emit xts planes + wts W-fragments; folded squash
    pass_z<0><<<240, 512, 0, stream>>>(x, W, xts, wts, oacc, nullptr,
                                       sb, zb, cnt);
    // iter 1: softmax(pred . out0); folded squash-accumulate
    pass_z<1><<<240, 512, 0, stream>>>(x, W, xts, wts, oacc, nullptr,
                                       sb + 40960, zb + 1280, cnt + NC);
    // iter 2: softmax(pred . (out0+out1)); folded squash -> d_out
    pass_z<2><<<240, 512, 0, stream>>>(x, W, xts, wts, oacc, outf,
                                       sb + 2 * 40960, zb + 2 * 1280, cnt + 2 * NC);
}